// Round 7
// baseline (1055.972 us; speedup 1.0000x reference)
//
#include <hip/hip_runtime.h>
#include <hip/hip_bf16.h>
#include <hip/hip_fp16.h>

// B=8, C=256, H=W=64, N=4096.
// v5: occupancy fix. V read direct from L2 (no LDS staging; 1x reuse anyway),
//     K stays LDS-dbuf via gload_lds (2x reuse). LDS 70.7KB -> 37.9KB
//     => 3 blocks/CU. Proj chain unchanged from v4b.

#define BATCH 8
#define CH    256
#define NPIX  4096

typedef __attribute__((ext_vector_type(8))) short    short8;
typedef __attribute__((ext_vector_type(8))) _Float16 half8;
typedef __attribute__((ext_vector_type(4))) float    f32x4;

__device__ __forceinline__ short f2h_s(float v) {
  _Float16 h = (_Float16)v;
  return __builtin_bit_cast(short, h);
}

__device__ __forceinline__ void gload16(const void* g, void* lds) {
  __builtin_amdgcn_global_load_lds(
      (const __attribute__((address_space(1))) unsigned int*)g,
      (__attribute__((address_space(3))) unsigned int*)lds, 16, 0, 0);
}

// ---------------- prep: whl[m][o][0:256]=hi(w), [256:512]=lo(w) -------------
__global__ __launch_bounds__(256) void prep_whl(
    const float* __restrict__ wq, const float* __restrict__ wk,
    const float* __restrict__ wv, short* __restrict__ whl) {
  const int m = blockIdx.x >> 8;       // grid 768
  const int o = blockIdx.x & 255;
  const float* w = m == 0 ? wq : m == 1 ? wk : wv;
  const int t = threadIdx.x;           // t == c
  float v = w[o * 256 + t];
  _Float16 h = (_Float16)v;
  _Float16 lo = (_Float16)(v - (float)h);
  short* dst = whl + ((size_t)m * 256 + o) * 512;
  dst[t] = __builtin_bit_cast(short, h);
  dst[256 + t] = __builtin_bit_cast(short, lo);
}

// ---------------- transpose x: [B,C,N] f32 -> xT [B,N,C] fp16 ---------------
__global__ __launch_bounds__(256) void transpose_x(
    const float* __restrict__ x, short* __restrict__ xT) {
  __shared__ float tile[64][68];
  const int id = blockIdx.x;           // 8 * 64 * 4 = 2048
  const int b = id >> 8;
  const int r = id & 255;
  const int n0 = (r >> 2) * 64, c0 = (r & 3) * 64;
  const int t = threadIdx.x;
  const float* xb = x + (size_t)b * CH * NPIX;
#pragma unroll
  for (int pass = 0; pass < 4; ++pass) {
    int c = pass * 16 + (t >> 4);
    float4 v = *(const float4*)&xb[(size_t)(c0 + c) * NPIX + n0 + (t & 15) * 4];
    *(float4*)&tile[c][(t & 15) * 4] = v;
  }
  __syncthreads();
  const int px = t >> 2;
#pragma unroll
  for (int mi = 0; mi < 2; ++mi) {
    int m = (t & 3) + mi * 4;
    short8 hh;
#pragma unroll
    for (int e = 0; e < 8; ++e) hh[e] = f2h_s(tile[m * 8 + e][px]);
    *(short8*)&xT[((size_t)b * NPIX + n0 + px) * CH + c0 + m * 8] = hh;
  }
}

// ---------------- projection GEMM: out[px][o] = xT . W^T + b ----------------
// grid 1536 = 8 b x 3 which x 32 px-tiles x 2 o-tiles. 256 thr, 4 waves (M32).
__global__ __launch_bounds__(256) void proj_gemm(
    const short* __restrict__ xT, const short* __restrict__ whl,
    const float* __restrict__ bq, const float* __restrict__ bk,
    const float* __restrict__ bv,
    short* __restrict__ qh, short* __restrict__ ql,
    short* __restrict__ kh, short* __restrict__ vbuf) {
  __shared__ __align__(16) short smem[4 * 8192];   // 64KB: As dbuf + Bs dbuf

  const int id = blockIdx.x;
  const int b = id / 192;
  const int r = id % 192;
  const int which = r >> 6;
  const int r2 = r & 63;
  const int px0 = (r2 >> 1) * 128, o0 = (r2 & 1) * 128;
  const int t = threadIdx.x;
  const int w = t >> 6, l = t & 63;
  const int l15 = l & 15, q4 = l >> 4;

  const short* Asrc = xT + ((size_t)b * NPIX + px0) * CH;
  const short* Bsrc = whl + ((size_t)which * 256 + o0) * 512;

  const int srow = t >> 1;             // staging: 2 lanes per row
  const int scb = (t & 1) * 4;         // 4 chunks each

  f32x4 acc[2][8];
#pragma unroll
  for (int i = 0; i < 2; ++i)
#pragma unroll
    for (int j = 0; j < 8; ++j) acc[i][j] = (f32x4){0.f, 0.f, 0.f, 0.f};

  short8 ra[4], rb[4];
  // prologue: load step 0
#pragma unroll
  for (int i = 0; i < 4; ++i) {
    int c = scb + i;
    ra[i] = *(const short8*)&Asrc[(size_t)srow * CH + 0 + c * 8];
    rb[i] = *(const short8*)&Bsrc[(size_t)srow * 512 + 0 + c * 8];
  }

#pragma unroll 1
  for (int s = 0; s < 8; ++s) {
    const int cur = s & 1;
    short* Asb = smem + cur * 8192;
    short* Bsb = smem + 16384 + cur * 8192;
    // write staged regs (swizzled: chunk ^= row&7)
#pragma unroll
    for (int i = 0; i < 4; ++i) {
      int c = scb + i;
      int wb = srow * 128 + ((c ^ (srow & 7)) * 16);
      *(short8*)((char*)Asb + wb) = ra[i];
      *(short8*)((char*)Bsb + wb) = rb[i];
    }
    __syncthreads();
    // prefetch next step
    if (s < 7) {
      int sn = s + 1;
      const short* Ap = Asrc + (sn & 3) * 64;
      const short* Bp = Bsrc + sn * 64;
#pragma unroll
      for (int i = 0; i < 4; ++i) {
        int c = scb + i;
        ra[i] = *(const short8*)&Ap[(size_t)srow * CH + c * 8];
        rb[i] = *(const short8*)&Bp[(size_t)srow * 512 + c * 8];
      }
    }
    // compute
#pragma unroll
    for (int kk = 0; kk < 2; ++kk) {
      half8 a[2];
#pragma unroll
      for (int mb = 0; mb < 2; ++mb) {
        int row = w * 32 + mb * 16 + l15;
        int byte = row * 128 + (((kk * 4 + q4) ^ (l15 & 7)) * 16);
        a[mb] = *(const half8*)((const char*)Asb + byte);
      }
#pragma unroll
      for (int nb = 0; nb < 8; ++nb) {
        int row = nb * 16 + l15;
        int byte = row * 128 + (((kk * 4 + q4) ^ (l15 & 7)) * 16);
        half8 bf = *(const half8*)((const char*)Bsb + byte);
        acc[0][nb] = __builtin_amdgcn_mfma_f32_16x16x32_f16(a[0], bf, acc[0][nb], 0, 0, 0);
        acc[1][nb] = __builtin_amdgcn_mfma_f32_16x16x32_f16(a[1], bf, acc[1][nb], 0, 0, 0);
      }
    }
    __syncthreads();
  }

  // epilogue
  const float* bias = which == 0 ? bq : which == 1 ? bk : bv;
  if (which < 2) {
#pragma unroll
    for (int nb = 0; nb < 8; ++nb) {
      float bv_ = bias[o0 + nb * 16 + l15];
      int o = o0 + nb * 16 + l15;
#pragma unroll
      for (int mb = 0; mb < 2; ++mb) {
#pragma unroll
        for (int rr = 0; rr < 4; ++rr) {
          float v = acc[mb][nb][rr] + bv_;
          int px = px0 + w * 32 + mb * 16 + q4 * 4 + rr;
          size_t off = ((size_t)b * NPIX + px) * CH + o;
          _Float16 h = (_Float16)v;
          if (which == 0) {
            qh[off] = __builtin_bit_cast(short, h);
            ql[off] = f2h_s(v - (float)h);
          } else {
            kh[off] = __builtin_bit_cast(short, h);
          }
        }
      }
    }
  } else {
    // v: transpose through LDS -> [B,C,N] fp16
    short* lt = smem;                  // [128][136] = 34.8KB
    __syncthreads();
#pragma unroll
    for (int nb = 0; nb < 8; ++nb) {
      float bv_ = bias[o0 + nb * 16 + l15];
      int o = nb * 16 + l15;
#pragma unroll
      for (int mb = 0; mb < 2; ++mb) {
#pragma unroll
        for (int rr = 0; rr < 4; ++rr) {
          int px = w * 32 + mb * 16 + q4 * 4 + rr;
          lt[o * 136 + px] = f2h_s(acc[mb][nb][rr] + bv_);
        }
      }
    }
    __syncthreads();
    const int ot = t >> 1;
#pragma unroll
    for (int i = 0; i < 8; ++i) {
      int c = (t & 1) * 8 + i;
      short8 vv = *(const short8*)&lt[ot * 136 + c * 8];
      *(short8*)&vbuf[((size_t)b * CH + o0 + ot) * NPIX + px0 + c * 8] = vv;
    }
  }
}

// ---------------- attention (fp16 MFMA flash, V direct from L2) -------------
#define QBLK 64
#define KBLK 32

__global__ __launch_bounds__(256, 3) void attn_kernel(
    const short* __restrict__ qh, const short* __restrict__ ql,
    const short* __restrict__ kh, const short* __restrict__ vb,
    float* __restrict__ out) {
  __shared__ __align__(16) short khs[2][KBLK * CH];   // 2 x 16KB, XOR-swizzled
  __shared__ __align__(16) short ps[4][16][40];       // 5KB fp16 P

  const int phys = blockIdx.x;
  const int lid  = (phys & 7) * 64 + (phys >> 3);     // XCD owns one batch
  const int b  = lid >> 6;
  const int i0 = (lid & 63) * QBLK;

  const int t = threadIdx.x;
  const int w = t >> 6, l = t & 63;
  const int l15 = l & 15, q4 = l >> 4, cbase = q4 * 8;

  // Q fragments hi/lo fp16
  half8 qfh[8], qfl[8];
  {
    const size_t qrow = (size_t)b * NPIX + i0 + w * 16 + l15;
    const short* ph = qh + qrow * CH + cbase;
    const short* pl = ql + qrow * CH + cbase;
#pragma unroll
    for (int kc = 0; kc < 8; ++kc) {
      qfh[kc] = *(const half8*)(ph + kc * 32);
      qfl[kc] = *(const half8*)(pl + kc * 32);
    }
  }

  f32x4 o[16];
#pragma unroll
  for (int i = 0; i < 16; ++i) o[i] = (f32x4){0.f, 0.f, 0.f, 0.f};
  f32x4 o_l = (f32x4){0.f, 0.f, 0.f, 0.f};
  float m_r[4] = {-1e30f, -1e30f, -1e30f, -1e30f};

  half8 onesh;
#pragma unroll
  for (int e = 0; e < 8; ++e) onesh[e] = (_Float16)1.0f;

  const short* gk = kh + (size_t)b * NPIX * CH;
  // per-lane V base: row = l15 (+ nt*16), col offset cbase; [C][N] layout
  const short* gvl = vb + (size_t)b * CH * NPIX + (size_t)l15 * NPIX + cbase;

  // stage K tile j0 into buffer bn: wave issues 4 gload_lds (16B each)
  auto issue = [&](int j0, int bn) {
#pragma unroll
    for (int i = 0; i < 4; ++i) {
      const int ins = w * 4 + i;
      const int krow = ins * 2 + (l >> 5);
      const int kch = (l & 31) ^ (krow & 7);          // pre-swizzled source
      gload16(gk + ((size_t)(j0 + krow)) * CH + kch * 8,
              (short*)&khs[bn][0] + ins * 512);
    }
  };

  issue(0, 0);

#pragma unroll 1
  for (int j0 = 0; j0 < NPIX; j0 += KBLK) {
    const int cur = (j0 >> 5) & 1;
    asm volatile("s_waitcnt vmcnt(0)" ::: "memory");
    __syncthreads();
    if (j0 + KBLK < NPIX) issue(j0 + KBLK, cur ^ 1);

    // ---- QK^T: 2-pass (qh + ql) x kh, 4 independent chains ----
    f32x4 s0h = (f32x4){0.f, 0.f, 0.f, 0.f}, s0l = s0h, s1h = s0h, s1l = s0h;
    __builtin_amdgcn_s_setprio(1);
#pragma unroll
    for (int kc = 0; kc < 8; ++kc) {
      int byte0 = (l15 * 512 + (kc * 32 + cbase) * 2) ^ ((l15 & 7) << 4);
      int byte1 = ((l15 + 16) * 512 + (kc * 32 + cbase) * 2) ^ ((l15 & 7) << 4);
      half8 b0 = *(const half8*)((const char*)&khs[cur][0] + byte0);
      half8 b1 = *(const half8*)((const char*)&khs[cur][0] + byte1);
      s0h = __builtin_amdgcn_mfma_f32_16x16x32_f16(qfh[kc], b0, s0h, 0, 0, 0);
      s0l = __builtin_amdgcn_mfma_f32_16x16x32_f16(qfl[kc], b0, s0l, 0, 0, 0);
      s1h = __builtin_amdgcn_mfma_f32_16x16x32_f16(qfh[kc], b1, s1h, 0, 0, 0);
      s1l = __builtin_amdgcn_mfma_f32_16x16x32_f16(qfl[kc], b1, s1l, 0, 0, 0);
    }
    __builtin_amdgcn_s_setprio(0);
    f32x4 s0, s1;
#pragma unroll
    for (int rr = 0; rr < 4; ++rr) { s0[rr] = s0h[rr] + s0l[rr]; s1[rr] = s1h[rr] + s1l[rr]; }

    // ---- online softmax (max only; sums via ones-MFMA) ----
    float scale[4], p0[4], p1[4];
#pragma unroll
    for (int rr = 0; rr < 4; ++rr) {
      float tm = fmaxf(s0[rr], s1[rr]);
      tm = fmaxf(tm, __shfl_xor(tm, 1));
      tm = fmaxf(tm, __shfl_xor(tm, 2));
      tm = fmaxf(tm, __shfl_xor(tm, 4));
      tm = fmaxf(tm, __shfl_xor(tm, 8));
      if (tm > m_r[rr] + 8.f) {       // T13 defer-rescale
        scale[rr] = __expf(m_r[rr] - tm);
        m_r[rr] = tm;
      } else {
        scale[rr] = 1.f;
      }
      p0[rr] = __expf(s0[rr] - m_r[rr]);
      p1[rr] = __expf(s1[rr] - m_r[rr]);
    }
    if (scale[0] != 1.f || scale[1] != 1.f || scale[2] != 1.f || scale[3] != 1.f) {
#pragma unroll
      for (int nt = 0; nt < 16; ++nt) {
        o[nt][0] *= scale[0]; o[nt][1] *= scale[1];
        o[nt][2] *= scale[2]; o[nt][3] *= scale[3];
      }
      o_l[0] *= scale[0]; o_l[1] *= scale[1];
      o_l[2] *= scale[2]; o_l[3] *= scale[3];
    }

    // ---- P (fp16) -> LDS, then PV with V direct from global (L2) ----
#pragma unroll
    for (int rr = 0; rr < 4; ++rr) {
      ps[w][q4 * 4 + rr][l15]      = f2h_s(p0[rr]);
      ps[w][q4 * 4 + rr][l15 + 16] = f2h_s(p1[rr]);
    }
    half8 pa = *(const half8*)&ps[w][l15][cbase];
    o_l = __builtin_amdgcn_mfma_f32_16x16x32_f16(pa, onesh, o_l, 0, 0, 0);
#pragma unroll
    for (int half = 0; half < 2; ++half) {
      half8 vv[8];
#pragma unroll
      for (int q = 0; q < 8; ++q)
        vv[q] = *(const half8*)(gvl + (size_t)(half * 8 + q) * 16 * NPIX + j0);
      __builtin_amdgcn_s_setprio(1);
#pragma unroll
      for (int q = 0; q < 8; ++q)
        o[half * 8 + q] =
            __builtin_amdgcn_mfma_f32_16x16x32_f16(pa, vv[q], o[half * 8 + q], 0, 0, 0);
      __builtin_amdgcn_s_setprio(0);
    }
  }

  // ---- epilogue: out[b, c, i] = o / l ----
  float inv[4];
#pragma unroll
  for (int rr = 0; rr < 4; ++rr) inv[rr] = 1.f / o_l[rr];
  float* ob = out + (size_t)b * CH * NPIX + i0 + w * 16;
#pragma unroll
  for (int nt = 0; nt < 16; ++nt) {
    const int c = nt * 16 + l15;
#pragma unroll
    for (int rr = 0; rr < 4; ++rr)
      ob[(size_t)c * NPIX + q4 * 4 + rr] = o[nt][rr] * inv[rr];
  }
}

extern "C" void kernel_launch(void* const* d_in, const int* in_sizes, int n_in,
                              void* d_out, int out_size, void* d_ws, size_t ws_size,
                              hipStream_t stream) {
  const float* x  = (const float*)d_in[0];
  const float* wq = (const float*)d_in[1];
  const float* bq = (const float*)d_in[2];
  const float* wk = (const float*)d_in[3];
  const float* bk = (const float*)d_in[4];
  const float* wv = (const float*)d_in[5];
  const float* bv = (const float*)d_in[6];
  float* out = (float*)d_out;

  const size_t per = (size_t)BATCH * NPIX * CH;    // 8.39M elems
  short* xT  = (short*)d_ws;
  short* qhb = xT + per;
  short* qlb = qhb + per;
  short* khb = qlb + per;
  short* vbf = khb + per;                          // 5 x 16.8MB = 84MB
  short* whl = vbf + per;                          // + 0.79MB

  prep_whl<<<768, 256, 0, stream>>>(wq, wk, wv, whl);
  transpose_x<<<2048, 256, 0, stream>>>(x, xT);
  proj_gemm<<<1536, 256, 0, stream>>>(xT, whl, bq, bk, bv, qhb, qlb, khb, vbf);
  attn_kernel<<<512, 256, 0, stream>>>(qhb, qlb, khb, vbf, out);
}

// Round 9
// 976.873 us; speedup vs baseline: 1.0810x; 1.0810x over previous
//
#include <hip/hip_runtime.h>
#include <hip/hip_bf16.h>
#include <hip/hip_fp16.h>

// B=8, C=256, H=W=64, N=4096.
// v6: v5 structure (V direct from L2, K LDS-dbuf via gload_lds) but WITHOUT
//     the launch_bounds min-waves clamp that forced 84 VGPRs + spills.
//     V loads in batches of 4 to trim VGPR pressure.

#define BATCH 8
#define CH    256
#define NPIX  4096

typedef __attribute__((ext_vector_type(8))) short    short8;
typedef __attribute__((ext_vector_type(8))) _Float16 half8;
typedef __attribute__((ext_vector_type(4))) float    f32x4;

__device__ __forceinline__ short f2h_s(float v) {
  _Float16 h = (_Float16)v;
  return __builtin_bit_cast(short, h);
}

__device__ __forceinline__ void gload16(const void* g, void* lds) {
  __builtin_amdgcn_global_load_lds(
      (const __attribute__((address_space(1))) unsigned int*)g,
      (__attribute__((address_space(3))) unsigned int*)lds, 16, 0, 0);
}

// ---------------- prep: whl[m][o][0:256]=hi(w), [256:512]=lo(w) -------------
__global__ __launch_bounds__(256) void prep_whl(
    const float* __restrict__ wq, const float* __restrict__ wk,
    const float* __restrict__ wv, short* __restrict__ whl) {
  const int m = blockIdx.x >> 8;       // grid 768
  const int o = blockIdx.x & 255;
  const float* w = m == 0 ? wq : m == 1 ? wk : wv;
  const int t = threadIdx.x;           // t == c
  float v = w[o * 256 + t];
  _Float16 h = (_Float16)v;
  _Float16 lo = (_Float16)(v - (float)h);
  short* dst = whl + ((size_t)m * 256 + o) * 512;
  dst[t] = __builtin_bit_cast(short, h);
  dst[256 + t] = __builtin_bit_cast(short, lo);
}

// ---------------- transpose x: [B,C,N] f32 -> xT [B,N,C] fp16 ---------------
__global__ __launch_bounds__(256) void transpose_x(
    const float* __restrict__ x, short* __restrict__ xT) {
  __shared__ float tile[64][68];
  const int id = blockIdx.x;           // 8 * 64 * 4 = 2048
  const int b = id >> 8;
  const int r = id & 255;
  const int n0 = (r >> 2) * 64, c0 = (r & 3) * 64;
  const int t = threadIdx.x;
  const float* xb = x + (size_t)b * CH * NPIX;
#pragma unroll
  for (int pass = 0; pass < 4; ++pass) {
    int c = pass * 16 + (t >> 4);
    float4 v = *(const float4*)&xb[(size_t)(c0 + c) * NPIX + n0 + (t & 15) * 4];
    *(float4*)&tile[c][(t & 15) * 4] = v;
  }
  __syncthreads();
  const int px = t >> 2;
#pragma unroll
  for (int mi = 0; mi < 2; ++mi) {
    int m = (t & 3) + mi * 4;
    short8 hh;
#pragma unroll
    for (int e = 0; e < 8; ++e) hh[e] = f2h_s(tile[m * 8 + e][px]);
    *(short8*)&xT[((size_t)b * NPIX + n0 + px) * CH + c0 + m * 8] = hh;
  }
}

// ---------------- projection GEMM: out[px][o] = xT . W^T + b ----------------
// grid 1536 = 8 b x 3 which x 32 px-tiles x 2 o-tiles. 256 thr, 4 waves (M32).
__global__ __launch_bounds__(256) void proj_gemm(
    const short* __restrict__ xT, const short* __restrict__ whl,
    const float* __restrict__ bq, const float* __restrict__ bk,
    const float* __restrict__ bv,
    short* __restrict__ qh, short* __restrict__ ql,
    short* __restrict__ kh, short* __restrict__ vbuf) {
  __shared__ __align__(16) short smem[4 * 8192];   // 64KB: As dbuf + Bs dbuf

  const int id = blockIdx.x;
  const int b = id / 192;
  const int r = id % 192;
  const int which = r >> 6;
  const int r2 = r & 63;
  const int px0 = (r2 >> 1) * 128, o0 = (r2 & 1) * 128;
  const int t = threadIdx.x;
  const int w = t >> 6, l = t & 63;
  const int l15 = l & 15, q4 = l >> 4;

  const short* Asrc = xT + ((size_t)b * NPIX + px0) * CH;
  const short* Bsrc = whl + ((size_t)which * 256 + o0) * 512;

  const int srow = t >> 1;             // staging: 2 lanes per row
  const int scb = (t & 1) * 4;         // 4 chunks each

  f32x4 acc[2][8];
#pragma unroll
  for (int i = 0; i < 2; ++i)
#pragma unroll
    for (int j = 0; j < 8; ++j) acc[i][j] = (f32x4){0.f, 0.f, 0.f, 0.f};

  short8 ra[4], rb[4];
  // prologue: load step 0
#pragma unroll
  for (int i = 0; i < 4; ++i) {
    int c = scb + i;
    ra[i] = *(const short8*)&Asrc[(size_t)srow * CH + 0 + c * 8];
    rb[i] = *(const short8*)&Bsrc[(size_t)srow * 512 + 0 + c * 8];
  }

#pragma unroll 1
  for (int s = 0; s < 8; ++s) {
    const int cur = s & 1;
    short* Asb = smem + cur * 8192;
    short* Bsb = smem + 16384 + cur * 8192;
    // write staged regs (swizzled: chunk ^= row&7)
#pragma unroll
    for (int i = 0; i < 4; ++i) {
      int c = scb + i;
      int wb = srow * 128 + ((c ^ (srow & 7)) * 16);
      *(short8*)((char*)Asb + wb) = ra[i];
      *(short8*)((char*)Bsb + wb) = rb[i];
    }
    __syncthreads();
    // prefetch next step
    if (s < 7) {
      int sn = s + 1;
      const short* Ap = Asrc + (sn & 3) * 64;
      const short* Bp = Bsrc + sn * 64;
#pragma unroll
      for (int i = 0; i < 4; ++i) {
        int c = scb + i;
        ra[i] = *(const short8*)&Ap[(size_t)srow * CH + c * 8];
        rb[i] = *(const short8*)&Bp[(size_t)srow * 512 + c * 8];
      }
    }
    // compute
#pragma unroll
    for (int kk = 0; kk < 2; ++kk) {
      half8 a[2];
#pragma unroll
      for (int mb = 0; mb < 2; ++mb) {
        int row = w * 32 + mb * 16 + l15;
        int byte = row * 128 + (((kk * 4 + q4) ^ (l15 & 7)) * 16);
        a[mb] = *(const half8*)((const char*)Asb + byte);
      }
#pragma unroll
      for (int nb = 0; nb < 8; ++nb) {
        int row = nb * 16 + l15;
        int byte = row * 128 + (((kk * 4 + q4) ^ (l15 & 7)) * 16);
        half8 bf = *(const half8*)((const char*)Bsb + byte);
        acc[0][nb] = __builtin_amdgcn_mfma_f32_16x16x32_f16(a[0], bf, acc[0][nb], 0, 0, 0);
        acc[1][nb] = __builtin_amdgcn_mfma_f32_16x16x32_f16(a[1], bf, acc[1][nb], 0, 0, 0);
      }
    }
    __syncthreads();
  }

  // epilogue
  const float* bias = which == 0 ? bq : which == 1 ? bk : bv;
  if (which < 2) {
#pragma unroll
    for (int nb = 0; nb < 8; ++nb) {
      float bv_ = bias[o0 + nb * 16 + l15];
      int o = o0 + nb * 16 + l15;
#pragma unroll
      for (int mb = 0; mb < 2; ++mb) {
#pragma unroll
        for (int rr = 0; rr < 4; ++rr) {
          float v = acc[mb][nb][rr] + bv_;
          int px = px0 + w * 32 + mb * 16 + q4 * 4 + rr;
          size_t off = ((size_t)b * NPIX + px) * CH + o;
          _Float16 h = (_Float16)v;
          if (which == 0) {
            qh[off] = __builtin_bit_cast(short, h);
            ql[off] = f2h_s(v - (float)h);
          } else {
            kh[off] = __builtin_bit_cast(short, h);
          }
        }
      }
    }
  } else {
    // v: transpose through LDS -> [B,C,N] fp16
    short* lt = smem;                  // [128][136] = 34.8KB
    __syncthreads();
#pragma unroll
    for (int nb = 0; nb < 8; ++nb) {
      float bv_ = bias[o0 + nb * 16 + l15];
      int o = nb * 16 + l15;
#pragma unroll
      for (int mb = 0; mb < 2; ++mb) {
#pragma unroll
        for (int rr = 0; rr < 4; ++rr) {
          int px = w * 32 + mb * 16 + q4 * 4 + rr;
          lt[o * 136 + px] = f2h_s(acc[mb][nb][rr] + bv_);
        }
      }
    }
    __syncthreads();
    const int ot = t >> 1;
#pragma unroll
    for (int i = 0; i < 8; ++i) {
      int c = (t & 1) * 8 + i;
      short8 vv = *(const short8*)&lt[ot * 136 + c * 8];
      *(short8*)&vbuf[((size_t)b * CH + o0 + ot) * NPIX + px0 + c * 8] = vv;
    }
  }
}

// ---------------- attention (fp16 MFMA flash, V direct from L2) -------------
#define QBLK 64
#define KBLK 32

__global__ __launch_bounds__(256) void attn_kernel(
    const short* __restrict__ qh, const short* __restrict__ ql,
    const short* __restrict__ kh, const short* __restrict__ vb,
    float* __restrict__ out) {
  __shared__ __align__(16) short khs[2][KBLK * CH];   // 2 x 16KB, XOR-swizzled
  __shared__ __align__(16) short ps[4][16][40];       // 5KB fp16 P

  const int phys = blockIdx.x;
  const int lid  = (phys & 7) * 64 + (phys >> 3);     // XCD owns one batch
  const int b  = lid >> 6;
  const int i0 = (lid & 63) * QBLK;

  const int t = threadIdx.x;
  const int w = t >> 6, l = t & 63;
  const int l15 = l & 15, q4 = l >> 4, cbase = q4 * 8;

  // Q fragments hi/lo fp16
  half8 qfh[8], qfl[8];
  {
    const size_t qrow = (size_t)b * NPIX + i0 + w * 16 + l15;
    const short* ph = qh + qrow * CH + cbase;
    const short* pl = ql + qrow * CH + cbase;
#pragma unroll
    for (int kc = 0; kc < 8; ++kc) {
      qfh[kc] = *(const half8*)(ph + kc * 32);
      qfl[kc] = *(const half8*)(pl + kc * 32);
    }
  }

  f32x4 o[16];
#pragma unroll
  for (int i = 0; i < 16; ++i) o[i] = (f32x4){0.f, 0.f, 0.f, 0.f};
  f32x4 o_l = (f32x4){0.f, 0.f, 0.f, 0.f};
  float m_r[4] = {-1e30f, -1e30f, -1e30f, -1e30f};

  half8 onesh;
#pragma unroll
  for (int e = 0; e < 8; ++e) onesh[e] = (_Float16)1.0f;

  const short* gk = kh + (size_t)b * NPIX * CH;
  // per-lane V base: row = l15 (+ nt*16), col offset cbase; [C][N] layout
  const short* gvl = vb + (size_t)b * CH * NPIX + (size_t)l15 * NPIX + cbase;

  // stage K tile j0 into buffer bn: wave issues 4 gload_lds (16B each)
  auto issue = [&](int j0, int bn) {
#pragma unroll
    for (int i = 0; i < 4; ++i) {
      const int ins = w * 4 + i;
      const int krow = ins * 2 + (l >> 5);
      const int kch = (l & 31) ^ (krow & 7);          // pre-swizzled source
      gload16(gk + ((size_t)(j0 + krow)) * CH + kch * 8,
              (short*)&khs[bn][0] + ins * 512);
    }
  };

  issue(0, 0);

#pragma unroll 1
  for (int j0 = 0; j0 < NPIX; j0 += KBLK) {
    const int cur = (j0 >> 5) & 1;
    asm volatile("s_waitcnt vmcnt(0)" ::: "memory");
    __syncthreads();
    if (j0 + KBLK < NPIX) issue(j0 + KBLK, cur ^ 1);

    // ---- QK^T: 2-pass (qh + ql) x kh, 4 independent chains ----
    f32x4 s0h = (f32x4){0.f, 0.f, 0.f, 0.f}, s0l = s0h, s1h = s0h, s1l = s0h;
    __builtin_amdgcn_s_setprio(1);
#pragma unroll
    for (int kc = 0; kc < 8; ++kc) {
      int byte0 = (l15 * 512 + (kc * 32 + cbase) * 2) ^ ((l15 & 7) << 4);
      int byte1 = ((l15 + 16) * 512 + (kc * 32 + cbase) * 2) ^ ((l15 & 7) << 4);
      half8 b0 = *(const half8*)((const char*)&khs[cur][0] + byte0);
      half8 b1 = *(const half8*)((const char*)&khs[cur][0] + byte1);
      s0h = __builtin_amdgcn_mfma_f32_16x16x32_f16(qfh[kc], b0, s0h, 0, 0, 0);
      s0l = __builtin_amdgcn_mfma_f32_16x16x32_f16(qfl[kc], b0, s0l, 0, 0, 0);
      s1h = __builtin_amdgcn_mfma_f32_16x16x32_f16(qfh[kc], b1, s1h, 0, 0, 0);
      s1l = __builtin_amdgcn_mfma_f32_16x16x32_f16(qfl[kc], b1, s1l, 0, 0, 0);
    }
    __builtin_amdgcn_s_setprio(0);
    f32x4 s0, s1;
#pragma unroll
    for (int rr = 0; rr < 4; ++rr) { s0[rr] = s0h[rr] + s0l[rr]; s1[rr] = s1h[rr] + s1l[rr]; }

    // ---- online softmax (max only; sums via ones-MFMA) ----
    float scale[4], p0[4], p1[4];
#pragma unroll
    for (int rr = 0; rr < 4; ++rr) {
      float tm = fmaxf(s0[rr], s1[rr]);
      tm = fmaxf(tm, __shfl_xor(tm, 1));
      tm = fmaxf(tm, __shfl_xor(tm, 2));
      tm = fmaxf(tm, __shfl_xor(tm, 4));
      tm = fmaxf(tm, __shfl_xor(tm, 8));
      if (tm > m_r[rr] + 8.f) {       // T13 defer-rescale
        scale[rr] = __expf(m_r[rr] - tm);
        m_r[rr] = tm;
      } else {
        scale[rr] = 1.f;
      }
      p0[rr] = __expf(s0[rr] - m_r[rr]);
      p1[rr] = __expf(s1[rr] - m_r[rr]);
    }
    if (scale[0] != 1.f || scale[1] != 1.f || scale[2] != 1.f || scale[3] != 1.f) {
#pragma unroll
      for (int nt = 0; nt < 16; ++nt) {
        o[nt][0] *= scale[0]; o[nt][1] *= scale[1];
        o[nt][2] *= scale[2]; o[nt][3] *= scale[3];
      }
      o_l[0] *= scale[0]; o_l[1] *= scale[1];
      o_l[2] *= scale[2]; o_l[3] *= scale[3];
    }

    // ---- P (fp16) -> LDS, then PV with V direct from global (L2) ----
#pragma unroll
    for (int rr = 0; rr < 4; ++rr) {
      ps[w][q4 * 4 + rr][l15]      = f2h_s(p0[rr]);
      ps[w][q4 * 4 + rr][l15 + 16] = f2h_s(p1[rr]);
    }
    half8 pa = *(const half8*)&ps[w][l15][cbase];
    o_l = __builtin_amdgcn_mfma_f32_16x16x32_f16(pa, onesh, o_l, 0, 0, 0);
#pragma unroll
    for (int qb = 0; qb < 4; ++qb) {
      half8 vv[4];
#pragma unroll
      for (int q = 0; q < 4; ++q)
        vv[q] = *(const half8*)(gvl + (size_t)(qb * 4 + q) * 16 * NPIX + j0);
      __builtin_amdgcn_s_setprio(1);
#pragma unroll
      for (int q = 0; q < 4; ++q)
        o[qb * 4 + q] =
            __builtin_amdgcn_mfma_f32_16x16x32_f16(pa, vv[q], o[qb * 4 + q], 0, 0, 0);
      __builtin_amdgcn_s_setprio(0);
    }
  }

  // ---- epilogue: out[b, c, i] = o / l ----
  float inv[4];
#pragma unroll
  for (int rr = 0; rr < 4; ++rr) inv[rr] = 1.f / o_l[rr];
  float* ob = out + (size_t)b * CH * NPIX + i0 + w * 16;
#pragma unroll
  for (int nt = 0; nt < 16; ++nt) {
    const int c = nt * 16 + l15;
#pragma unroll
    for (int rr = 0; rr < 4; ++rr)
      ob[(size_t)c * NPIX + q4 * 4 + rr] = o[nt][rr] * inv[rr];
  }
}

extern "C" void kernel_launch(void* const* d_in, const int* in_sizes, int n_in,
                              void* d_out, int out_size, void* d_ws, size_t ws_size,
                              hipStream_t stream) {
  const float* x  = (const float*)d_in[0];
  const float* wq = (const float*)d_in[1];
  const float* bq = (const float*)d_in[2];
  const float* wk = (const float*)d_in[3];
  const float* bk = (const float*)d_in[4];
  const float* wv = (const float*)d_in[5];
  const float* bv = (const float*)d_in[6];
  float* out = (float*)d_out;

  const size_t per = (size_t)BATCH * NPIX * CH;    // 8.39M elems
  short* xT  = (short*)d_ws;
  short* qhb = xT + per;
  short* qlb = qhb + per;
  short* khb = qlb + per;
  short* vbf = khb + per;                          // 5 x 16.8MB = 84MB
  short* whl = vbf + per;                          // + 0.79MB

  prep_whl<<<768, 256, 0, stream>>>(wq, wk, wv, whl);
  transpose_x<<<2048, 256, 0, stream>>>(x, xT);
  proj_gemm<<<1536, 256, 0, stream>>>(xT, whl, bq, bk, bv, qhb, qlb, khb, vbf);
  attn_kernel<<<512, 256, 0, stream>>>(qhb, qlb, khb, vbf, out);
}